// Round 5
// baseline (98.246 us; speedup 1.0000x reference)
//
#include <hip/hip_runtime.h>
#include <stdint.h>

typedef int   int4v   __attribute__((ext_vector_type(4)));
typedef float float4v __attribute__((ext_vector_type(4)));

static constexpr int DIM = 4096;          // N = IN = OUT
static constexpr int BM  = 256, BN = 256; // block tile
static constexpr int BK  = 128;           // K-step bytes (2 MFMA k-steps of K=64)
static constexpr int NKT = DIM / BK;      // 32

// ---------------- quantization kernels ----------------
__global__ __launch_bounds__(256) void quant_act_kernel(
    const float* __restrict__ x, const float* __restrict__ s_ptr,
    const int* __restrict__ zp_ptr, int* __restrict__ out, int n4) {
  const float s  = s_ptr[0];
  const int   zp = zp_ptr[0];
  int idx    = blockIdx.x * blockDim.x + threadIdx.x;
  int stride = gridDim.x * blockDim.x;
  for (int i = idx; i < n4; i += stride) {
    float4v v = reinterpret_cast<const float4v*>(x)[i];
    int packed = 0;
#pragma unroll
    for (int j = 0; j < 4; ++j) {
      int q = (int)rintf(v[j] / s) + zp;
      q = min(max(q, 0), 255);
      q -= zp;
      packed |= (q & 255) << (8 * j);
    }
    out[i] = packed;
  }
}

__global__ __launch_bounds__(256) void quant_wgt_kernel(
    const float* __restrict__ w, const float* __restrict__ ws,
    const int* __restrict__ wzp, int* __restrict__ out, int n4) {
  int idx    = blockIdx.x * blockDim.x + threadIdx.x;
  int stride = gridDim.x * blockDim.x;
  for (int i = idx; i < n4; i += stride) {
    const int row = i >> 10;
    const float s = ws[row];
    const int  zp = wzp[row];
    float4v v = reinterpret_cast<const float4v*>(w)[i];
    int packed = 0;
#pragma unroll
    for (int j = 0; j < 4; ++j) {
      int q = (int)rintf(v[j] / s) + zp;
      q = min(max(q, 0), 255);
      q -= zp;
      packed |= (q & 255) << (8 * j);
    }
    out[i] = packed;
  }
}

// ---- int8 GEMM: m201-faithful 4-phase/K-tile, fine 2-chunk/phase staging,
//      prefetch-distance-2, derived counted vmcnt(4) at tile boundary only.
// Stage stream (per wave, 2 chunks/phase, continuous):
//   ph1(kt): A2,B2 of kt+1   ph2(kt): A3,B3 of kt+1   [other buffer]
//   ph3(kt): A0,B0 of kt+2   ph4(kt): A1,B1 of kt+2   [cur buffer - dead after ph2 lgkm]
// Boundary wait (end ph4): 4 newest (kt+2 first half) in flight, all of kt+1 landed.

#define MFMA_QUAD(AF, MH, NL)                                                  \
  __builtin_amdgcn_s_setprio(1);                                               \
  _Pragma("unroll") for (int kk = 0; kk < 2; ++kk)                             \
  _Pragma("unroll") for (int m = 0; m < 4; ++m)                                \
  _Pragma("unroll") for (int n = 0; n < 2; ++n)                                \
      acc[(MH)*4 + m][(NL) + n] = __builtin_amdgcn_mfma_i32_16x16x64_i8(       \
          AF[m][kk], bf[(NL) + n][kk], acc[(MH)*4 + m][(NL) + n], 0, 0, 0);    \
  __builtin_amdgcn_s_setprio(0);

__global__ __launch_bounds__(512) void gemm_i8_m201(
    const signed char* __restrict__ A, const signed char* __restrict__ B,
    const float* __restrict__ s_act, const float* __restrict__ w_scale,
    const float* __restrict__ bias, float* __restrict__ C) {
  extern __shared__ signed char smem[];  // 2 buffers x (A 32K + B 32K) = 128 KiB

  const int tid  = threadIdx.x;
  const int w    = tid >> 6;            // wave 0..7
  const int lane = tid & 63;
  const int wr = w >> 2, wc = w & 3;    // 2 x 4 wave grid; wave tile 128x64
  const int l15 = lane & 15, lhi = lane >> 4;
  const int swk = (l15 & 7) << 4;       // read-side XOR swizzle key ((row&7)<<4)

  const int srow = lane >> 3;                           // staging row within 8-row chunk
  const int scol = ((lane & 7) ^ (lane >> 3)) << 4;     // pre-swizzled global col

  const int tileM = blockIdx.y * BM;
  const int tileN = blockIdx.x * BN;

  auto stageA = [&](int i, int t) {
    signed char* dst = smem + (t & 1) * 65536;
    const int c = 4 * w + i;
    const size_t g = (size_t)(tileM + c * 8 + srow) * DIM + (size_t)t * BK + scol;
    __builtin_amdgcn_global_load_lds(
        (const __attribute__((address_space(1))) void*)(A + g),
        (__attribute__((address_space(3))) void*)(dst + c * 1024), 16, 0, 0);
  };
  auto stageB = [&](int i, int t) {
    signed char* dst = smem + (t & 1) * 65536 + 32768;
    const int c = 4 * w + i;
    const size_t g = (size_t)(tileN + c * 8 + srow) * DIM + (size_t)t * BK + scol;
    __builtin_amdgcn_global_load_lds(
        (const __attribute__((address_space(1))) void*)(B + g),
        (__attribute__((address_space(3))) void*)(dst + c * 1024), 16, 0, 0);
  };
  auto rdA = [&](const signed char* aL, int mh, int m, int kk) -> int4v {
    const int r = wr * 128 + (mh * 4 + m) * 16 + l15;
    return *(const int4v*)(aL + r * BK + ((kk * 64 + lhi * 16) ^ swk));
  };
  auto rdB = [&](const signed char* bL, int nidx, int kk) -> int4v {
    const int r = wc * 64 + nidx * 16 + l15;
    return *(const int4v*)(bL + r * BK + ((kk * 64 + lhi * 16) ^ swk));
  };

  int4v acc[8][4] = {};
  int4v afLo[4][2];   // A m-tiles 0-3 (rows wr*128+0..63)
  int4v afHi[4][2];   // A m-tiles 4-7
  int4v bf[4][2];     // B n-tiles 0-3

  // ---- prologue: tile0 fully + first half of tile1; steady-state ledger = 4 outstanding
#pragma unroll
  for (int i = 0; i < 4; ++i) { stageA(i, 0); stageB(i, 0); }
  stageA(0, 1); stageB(0, 1); stageA(1, 1); stageB(1, 1);
  asm volatile("s_waitcnt vmcnt(4)" ::: "memory");
  __builtin_amdgcn_s_barrier();

  for (int kt = 0; kt < NKT; ++kt) {
    const signed char* aC = smem + (kt & 1) * 65536;
    const signed char* bC = aC + 32768;
    const bool s1 = (kt + 1 < NKT);
    const bool s2 = (kt + 2 < NKT);

    // ---- ph1: read A-mh0(8)+B-n01(4); stage A2,B2 of kt+1; MFMA (0,0)
#pragma unroll
    for (int m = 0; m < 4; ++m) { afLo[m][0] = rdA(aC, 0, m, 0); afLo[m][1] = rdA(aC, 0, m, 1); }
#pragma unroll
    for (int n = 0; n < 2; ++n) { bf[n][0] = rdB(bC, n, 0); bf[n][1] = rdB(bC, n, 1); }
    if (s1) { stageA(2, kt + 1); stageB(2, kt + 1); }
    __builtin_amdgcn_s_barrier();
    asm volatile("s_waitcnt lgkmcnt(0)" ::: "memory");
    MFMA_QUAD(afLo, 0, 0)
    __builtin_amdgcn_s_barrier();

    // ---- ph2: read A-mh1(8)+B-n23(4); stage A3,B3 of kt+1; MFMA (0,1)
#pragma unroll
    for (int m = 0; m < 4; ++m) { afHi[m][0] = rdA(aC, 1, m, 0); afHi[m][1] = rdA(aC, 1, m, 1); }
#pragma unroll
    for (int n = 2; n < 4; ++n) { bf[n][0] = rdB(bC, n, 0); bf[n][1] = rdB(bC, n, 1); }
    if (s1) { stageA(3, kt + 1); stageB(3, kt + 1); }
    __builtin_amdgcn_s_barrier();
    asm volatile("s_waitcnt lgkmcnt(0)" ::: "memory");   // all cur-buffer reads done
    MFMA_QUAD(afLo, 0, 2)
    __builtin_amdgcn_s_barrier();                        // cur buffer now dead -> stageable

    // ---- ph3: stage A0,B0 of kt+2 into cur; MFMA (1,0)
    if (s2) { stageA(0, kt + 2); stageB(0, kt + 2); }
    __builtin_amdgcn_s_barrier();
    MFMA_QUAD(afHi, 1, 0)
    __builtin_amdgcn_s_barrier();

    // ---- ph4: stage A1,B1 of kt+2; MFMA (1,1); counted boundary wait
    if (s2) { stageA(1, kt + 2); stageB(1, kt + 2); }
    __builtin_amdgcn_s_barrier();
    MFMA_QUAD(afHi, 1, 2)
    if (s2) {
      asm volatile("s_waitcnt vmcnt(4)" ::: "memory");   // kt+1 landed; kt+2 half in flight
    } else {
      asm volatile("s_waitcnt vmcnt(0)" ::: "memory");   // tail: kt+1's last chunks must land
    }
    __builtin_amdgcn_s_barrier();
  }

  // ---- epilogue: C/D layout col=lane&15, row=(lane>>4)*4+j
  const float sa = s_act[0];
#pragma unroll
  for (int n = 0; n < 4; ++n) {
    const int col = tileN + wc * 64 + n * 16 + l15;
    const float sc = sa * w_scale[col];
    const float bs = bias[col];
#pragma unroll
    for (int m = 0; m < 8; ++m) {
      const int rbase = tileM + wr * 128 + m * 16 + lhi * 4;
#pragma unroll
      for (int j = 0; j < 4; ++j)
        C[(size_t)(rbase + j) * DIM + col] = (float)acc[m][n][j] * sc + bs;
    }
  }
}

// ---------------- launch ----------------
extern "C" void kernel_launch(void* const* d_in, const int* in_sizes, int n_in,
                              void* d_out, int out_size, void* d_ws, size_t ws_size,
                              hipStream_t stream) {
  const float* x    = (const float*)d_in[0];
  const float* w    = (const float*)d_in[1];
  const float* bias = (const float*)d_in[2];
  const float* a_s  = (const float*)d_in[3];
  const int*   a_zp = (const int*)d_in[4];
  const float* w_s  = (const float*)d_in[5];
  const int*   w_zp = (const int*)d_in[6];
  float* out = (float*)d_out;

  signed char* a8 = (signed char*)d_ws;
  signed char* b8 = a8 + (size_t)DIM * DIM;

  const int n4 = DIM * DIM / 4;
  quant_act_kernel<<<2048, 256, 0, stream>>>(x, a_s, a_zp, (int*)a8, n4);
  quant_wgt_kernel<<<2048, 256, 0, stream>>>(w, w_s, w_zp, (int*)b8, n4);

  (void)hipFuncSetAttribute((const void*)gemm_i8_m201,
                            hipFuncAttributeMaxDynamicSharedMemorySize, 131072);
  dim3 grid(DIM / BN, DIM / BM);  // 16 x 16
  gemm_i8_m201<<<grid, 512, 131072, stream>>>(a8, b8, a_s, w_s, bias, out);
}